// Round 15
// baseline (530.598 us; speedup 1.0000x reference)
//
#include <hip/hip_runtime.h>
#include <hip/hip_bf16.h>

#define DEV static __device__ __forceinline__

typedef __attribute__((ext_vector_type(4))) float f32x4;
typedef __attribute__((ext_vector_type(8))) short bf16x8;

DEV unsigned short f2bf(float x){
  __hip_bfloat16 h = __float2bfloat16(x);
  return __builtin_bit_cast(unsigned short, h);
}
DEV float b2f(unsigned short u){
  __hip_bfloat16 h = __builtin_bit_cast(__hip_bfloat16, u);
  return __bfloat162float(h);
}
DEV float softplus_f(float x){ return fmaxf(x, 0.f) + log1pf(expf(-fabsf(x))); }

DEV void gload16(const void* g, void* l){
  __builtin_amdgcn_global_load_lds((const __attribute__((address_space(1))) void*)g,
                                   (__attribute__((address_space(3))) void*)l, 16, 0, 0);
}

template<int N> DEV void waitcnt_vm(){
  if constexpr (N == 0) asm volatile("s_waitcnt vmcnt(0)" ::: "memory");
  else if constexpr (N == 3) asm volatile("s_waitcnt vmcnt(3)" ::: "memory");
  else if constexpr (N == 5) asm volatile("s_waitcnt vmcnt(5)" ::: "memory");
  else if constexpr (N == 6) asm volatile("s_waitcnt vmcnt(6)" ::: "memory");
  else if constexpr (N == 7) asm volatile("s_waitcnt vmcnt(7)" ::: "memory");
  else if constexpr (N == 8) asm volatile("s_waitcnt vmcnt(8)" ::: "memory");
  else if constexpr (N == 9) asm volatile("s_waitcnt vmcnt(9)" ::: "memory");
}

// ---------------------------------------------------------------------------
// Merged prep: [0,1024) four 512x512 transposes; [1024,17024) w_dec transpose;
// [17024,19072) gather (2 rows/block); 19072 pad-row zeroing.  256 thr.
__global__ void k_prep(const float* __restrict__ w_mass, const float* __restrict__ w_f1,
                       const float* __restrict__ w_f2, const float* __restrict__ w_dec,
                       const int* __restrict__ x, const float* __restrict__ emb,
                       unsigned short* __restrict__ wTmass, unsigned short* __restrict__ wTf1,
                       unsigned short* __restrict__ wTf2, unsigned short* __restrict__ wTdec,
                       unsigned short* __restrict__ eA,
                       unsigned short* __restrict__ m16_pad, unsigned short* __restrict__ act_pad0){
  __shared__ float t[32][33];
  const int b = blockIdx.x;
  const int tid = threadIdx.x;
  if (b >= 17024){
    const int local = b - 17024;
    if (local == 2048){
      if (tid < 128){
        const ushort4 z = {0, 0, 0, 0};
        ((ushort4*)m16_pad)[tid] = z;
        ((ushort4*)act_pad0)[tid] = z;
      }
      return;
    }
    const int row = local * 2 + (tid >> 7);
    const int c   = tid & 127;
    const int idx = x[row];
    const float4 v = ((const float4*)(emb + (size_t)idx * 512))[c];
    ushort4 o; o.x = f2bf(v.x); o.y = f2bf(v.y); o.z = f2bf(v.z); o.w = f2bf(v.w);
    ((ushort4*)(eA + (size_t)row * 512))[c] = o;
    return;
  }
  const float* in; unsigned short* out; int K, N, bx, by;
  if (b < 1024){
    const int z = b >> 8, idx = b & 255;
    bx = idx & 15; by = idx >> 4; K = 512; N = 512;
    switch (z){
      case 0:  in = w_mass;            out = wTmass;            break;
      case 1:  in = w_f1;              out = wTf1;              break;
      case 2:  in = w_f1 + 512 * 512;  out = wTf1 + 512 * 512;  break;
      default: in = w_f2;              out = wTf2;              break;
    }
  } else {
    const int local = b - 1024;
    bx = local % 1000; by = local / 1000; K = 512; N = 32000;
    in = w_dec; out = wTdec;
  }
  const int nt = bx * 32, kt = by * 32;
  const int r  = tid >> 3;
  const int c4 = (tid & 7) * 4;
  const float4 v = *(const float4*)(in + (size_t)(kt + r) * N + nt + c4);
  t[r][c4+0] = v.x; t[r][c4+1] = v.y; t[r][c4+2] = v.z; t[r][c4+3] = v.w;
  __syncthreads();
  ushort4 o;
  o.x = f2bf(t[c4+0][r]); o.y = f2bf(t[c4+1][r]);
  o.z = f2bf(t[c4+2][r]); o.w = f2bf(t[c4+3][r]);
  *(ushort4*)(out + (size_t)(nt + r) * K + kt + c4) = o;
}

// ---------------------------------------------------------------------------
// Pipelined GEMM (mass): C = A @ Bt^T; EPI 1: softplus(x+bias)+eps -> bf16 outBf.
template<int BM, int BN, int WM, int WN, int NT, int EPI>
__global__ __launch_bounds__(WM * WN * 64, 2)
void gemmP(const unsigned short* __restrict__ A, const unsigned short* __restrict__ Bt,
           const float* __restrict__ bias, unsigned short* __restrict__ outBf,
           int N, int nbx)
{
  constexpr int NW = WM * WN;
  constexpr int FA = BM / (WM * 16);
  constexpr int FB = BN / (WN * 16);
  constexpr int GA = BM / (8 * NW);
  constexpr int GB = BN / (8 * NW);
  constexpr int VC = GA + GB;
  constexpr int LA = BM * 64;
  constexpr int LB = BN * 64;
  constexpr int K  = NT * 64;

  extern __shared__ unsigned short lds[];
  const int tid  = threadIdx.x;
  const int lane = tid & 63;
  const int w    = tid >> 6;
  const int wr   = w / WN;
  const int wc   = w % WN;

  const int nwg = gridDim.x;
  const int cpx = nwg >> 3;
  const int swz = ((int)blockIdx.x & 7) * cpx + ((int)blockIdx.x >> 3);
  const int rowA0 = (swz % nbx) * BM;
  const int rowB0 = (swz / nbx) * BN;

  const int subr = lane >> 3;
  const int cc   = lane & 7;

  auto stage = [&](int kt, int buf){
    unsigned short* la = lds + buf * (LA + LB);
    unsigned short* lb = la + LA;
    const int k0 = kt * 64;
    #pragma unroll
    for (int i = 0; i < GA; i++){
      const int sub = w * GA + i;
      const int r   = sub * 8 + subr;
      const int cs  = cc ^ (r & 7);
      gload16(A + (size_t)(rowA0 + r) * K + k0 + cs * 8, la + sub * 512);
    }
    #pragma unroll
    for (int i = 0; i < GB; i++){
      const int sub = w * GB + i;
      const int r   = sub * 8 + subr;
      const int cs  = cc ^ (r & 7);
      gload16(Bt + (size_t)(rowB0 + r) * K + k0 + cs * 8, lb + sub * 512);
    }
  };

  f32x4 acc[FA][FB];
  const f32x4 z = {0.f, 0.f, 0.f, 0.f};
  #pragma unroll
  for (int i = 0; i < FA; i++)
    #pragma unroll
    for (int j = 0; j < FB; j++) acc[i][j] = z;

  stage(0, 0);
  stage(1, 1);
  waitcnt_vm<VC>();
  __builtin_amdgcn_s_barrier();
  __builtin_amdgcn_sched_barrier(0);

  #pragma unroll
  for (int t = 0; t < NT; ++t){
    const int cur = t & 1;
    const unsigned short* la = lds + cur * (LA + LB);
    const unsigned short* lb = la + LA;

    #pragma unroll
    for (int ks = 0; ks < 2; ks++){
      bf16x8 af[FA], bfr[FB];
      #pragma unroll
      for (int i = 0; i < FA; i++){
        const int ra = wr * (BM / WM) + i * 16 + (lane & 15);
        const int ka = (ks * 4 + (lane >> 4)) ^ (ra & 7);
        af[i] = *(const bf16x8*)(la + ra * 64 + ka * 8);
      }
      #pragma unroll
      for (int j = 0; j < FB; j++){
        const int rb = wc * (BN / WN) + j * 16 + (lane & 15);
        const int kb = (ks * 4 + (lane >> 4)) ^ (rb & 7);
        bfr[j] = *(const bf16x8*)(lb + rb * 64 + kb * 8);
      }
      if (ks == 1){
        asm volatile("s_waitcnt lgkmcnt(0)" ::: "memory");
        __builtin_amdgcn_sched_barrier(0);
        __builtin_amdgcn_s_barrier();
        __builtin_amdgcn_sched_barrier(0);
        if (t + 2 < NT) stage(t + 2, cur);
      }
      __builtin_amdgcn_s_setprio(1);
      #pragma unroll
      for (int i = 0; i < FA; i++)
        #pragma unroll
        for (int j = 0; j < FB; j++)
          acc[i][j] = __builtin_amdgcn_mfma_f32_16x16x32_bf16(af[i], bfr[j], acc[i][j], 0, 0, 0);
      __builtin_amdgcn_s_setprio(0);
    }

    if (t < NT - 1){
      if (t + 2 < NT) waitcnt_vm<VC>();
      else            waitcnt_vm<0>();
      __builtin_amdgcn_s_barrier();
      __builtin_amdgcn_sched_barrier(0);
    }
  }

  const int r4 = (lane >> 4) * 4;
  const int cl = lane & 15;
  #pragma unroll
  for (int j = 0; j < FB; j++){
    const int col = rowB0 + wc * (BN / WN) + j * 16 + cl;
    const float bv = bias[col];
    #pragma unroll
    for (int i = 0; i < FA; i++){
      const int row0 = rowA0 + wr * (BM / WM) + i * 16 + r4;
      #pragma unroll
      for (int r = 0; r < 4; r++){
        float v = softplus_f(acc[i][j][r] + bv) + 1e-6f;
        outBf[(size_t)(row0 + r) * N + col] = f2bf(v);
      }
    }
  }
}

// ---------------------------------------------------------------------------
// Decoder GEMM (R14, unchanged): 256x128 tile, BK=32, NT=16, 8 waves,
// dbuf 48 KiB, __launch_bounds__(512,4) -> 2 blocks/CU, vectorized epilogue.
__global__ __launch_bounds__(512, 4)
void gemmDec(const unsigned short* __restrict__ A, const unsigned short* __restrict__ Bt,
             const float* __restrict__ bias, float* __restrict__ out, int N, int nbx)
{
  constexpr int BM = 256, BN = 128, BK = 32, NT = 16;
  constexpr int LA = BM * BK;
  constexpr int LB = BN * BK;
  constexpr int BUF = LA + LB;
  constexpr int K = NT * BK;

  extern __shared__ unsigned short lds[];
  const int tid  = threadIdx.x;
  const int lane = tid & 63;
  const int w    = tid >> 6;
  const int wr   = w >> 1;
  const int wc   = w & 1;

  const int nwg = gridDim.x;
  const int cpx = nwg >> 3;
  const int swz = ((int)blockIdx.x & 7) * cpx + ((int)blockIdx.x >> 3);
  const int rowA0 = (swz % nbx) * BM;
  const int rowB0 = (swz / nbx) * BN;

  const int srow = lane >> 2;
  const int cch  = lane & 3;

  auto stage = [&](int kt, int buf){
    unsigned short* la = lds + buf * BUF;
    unsigned short* lb = la + LA;
    const int k0 = kt * BK;
    #pragma unroll
    for (int i = 0; i < 2; i++){
      const int sub = w * 2 + i;
      const int r   = sub * 16 + srow;
      const int cs  = cch ^ ((r >> 1) & 3);
      gload16(A + (size_t)(rowA0 + r) * K + k0 + cs * 8, la + sub * 512);
    }
    {
      const int sub = w;
      const int r   = sub * 16 + srow;
      const int cs  = cch ^ ((r >> 1) & 3);
      gload16(Bt + (size_t)(rowB0 + r) * K + k0 + cs * 8, lb + sub * 512);
    }
  };

  f32x4 acc[4][4];
  const f32x4 z = {0.f, 0.f, 0.f, 0.f};
  #pragma unroll
  for (int i = 0; i < 4; i++)
    #pragma unroll
    for (int j = 0; j < 4; j++) acc[i][j] = z;

  stage(0, 0);
  stage(1, 1);
  waitcnt_vm<3>();
  __builtin_amdgcn_s_barrier();
  __builtin_amdgcn_sched_barrier(0);

  const int kq = lane >> 4;

  #pragma unroll
  for (int t = 0; t < NT; ++t){
    const int cur = t & 1;
    const unsigned short* la = lds + cur * BUF;
    const unsigned short* lb = la + LA;

    bf16x8 a[4], b[4];
    #pragma unroll
    for (int i = 0; i < 4; i++){
      const int ra = wr * 64 + i * 16 + (lane & 15);
      const int kc = kq ^ ((ra >> 1) & 3);
      a[i] = *(const bf16x8*)(la + ra * 32 + kc * 8);
    }
    #pragma unroll
    for (int j = 0; j < 4; j++){
      const int rb = wc * 64 + j * 16 + (lane & 15);
      const int kc = kq ^ ((rb >> 1) & 3);
      b[j] = *(const bf16x8*)(lb + rb * 32 + kc * 8);
    }

    asm volatile("s_waitcnt lgkmcnt(0)" ::: "memory");
    __builtin_amdgcn_sched_barrier(0);
    __builtin_amdgcn_s_barrier();
    __builtin_amdgcn_sched_barrier(0);
    if (t + 2 < NT) stage(t + 2, cur);

    __builtin_amdgcn_s_setprio(1);
    #pragma unroll
    for (int i = 0; i < 4; i++)
      #pragma unroll
      for (int j = 0; j < 4; j++)
        acc[i][j] = __builtin_amdgcn_mfma_f32_16x16x32_bf16(a[i], b[j], acc[i][j], 0, 0, 0);
    __builtin_amdgcn_s_setprio(0);

    if (t < NT - 1){
      if (t + 2 < NT) waitcnt_vm<3>();
      else            waitcnt_vm<0>();
      __builtin_amdgcn_s_barrier();
      __builtin_amdgcn_sched_barrier(0);
    }
  }

  float* lds_f = (float*)lds;
  const int r4 = (lane >> 4) * 4;
  const int cl = lane & 15;
  #pragma unroll
  for (int c = 0; c < 4; c++){
    __syncthreads();
    if (wr == c){
      #pragma unroll
      for (int j = 0; j < 4; j++){
        const int col = wc * 64 + j * 16 + cl;
        #pragma unroll
        for (int i = 0; i < 4; i++){
          const int rowl = i * 16 + r4;
          #pragma unroll
          for (int r = 0; r < 4; r++)
            lds_f[(rowl + r) * 132 + col] = acc[i][j][r];
        }
      }
    }
    __syncthreads();
    #pragma unroll
    for (int k = 0; k < 4; k++){
      const int q   = tid + 512 * k;
      const int row = q >> 5;
      const int c0  = (q & 31) * 4;
      float4 v = *(float4*)&lds_f[row * 132 + c0];
      const float4 bv = *(const float4*)&bias[rowB0 + c0];
      v.x += bv.x; v.y += bv.y; v.z += bv.z; v.w += bv.w;
      *(float4*)&out[(size_t)(rowA0 + c * 64 + row) * N + rowB0 + c0] = v;
    }
  }
}

// ---------------------------------------------------------------------------
// Fused flux kernels (R15: BM 64 -> 128), 128x64 tile, dual accumulators via
// shifted-A fragments.  A staged rows rowA0+0..135 (17 subtiles; 3 benign
// dup-writes of sub 16); ds_reads use rows 0..128 only.
// MODE 0: act[s] = tanh(m[s]@W1a + m[s+1]@W1b + b1) -> act_pad[s+1].
// MODE 1: m = max(m + dt*(sp(F[s-1]) - sp(F[s])), eps), bf16 carry.
template<int MODE>
__global__ __launch_bounds__(256, 2)
void fluxK(const unsigned short* __restrict__ A, const unsigned short* __restrict__ Bt,
           const float* __restrict__ bias, const float* __restrict__ cfl,
           unsigned short* __restrict__ m16, unsigned short* __restrict__ act_pad)
{
  constexpr int ASUB = 17;                    // 136 staged rows (need 129)
  constexpr int BSUB = (MODE == 0) ? 16 : 8;
  constexpr int GA = 5;                       // 4 waves x 5 = 20 slots, 3 dup
  constexpr int GB = (MODE == 0) ? 4 : 2;
  constexpr int VC = GA + GB;                 // 9 / 7
  constexpr int ABUF = ASUB * 512;
  constexpr int BBUF = BSUB * 512;
  constexpr int BUFSZ = ABUF + BBUF;

  extern __shared__ unsigned short lds[];
  const int tid  = threadIdx.x;
  const int lane = tid & 63;
  const int w    = tid >> 6;
  const int wr   = w >> 1, wc = w & 1;
  const int rowA0 = blockIdx.x * 128;
  const int col0  = blockIdx.y * 64;
  const int subr = lane >> 3;
  const int cc   = lane & 7;

  auto stage = [&](int kt, int buf){
    unsigned short* la = lds + buf * BUFSZ;
    unsigned short* lb = la + ABUF;
    const int k0 = kt * 64;
    #pragma unroll
    for (int i = 0; i < GA; i++){
      const int si  = w * GA + i;
      const int sub = si > 16 ? 16 : si;
      const int r   = sub * 8 + subr;
      const int cs  = cc ^ subr;
      gload16(A + (size_t)(rowA0 + r) * 512 + k0 + cs * 8, la + sub * 512);
    }
    #pragma unroll
    for (int i = 0; i < GB; i++){
      const int sub = w * GB + i;
      int grow;
      if (MODE == 0) grow = (sub < 8) ? (col0 + sub * 8 + subr)
                                      : (512 + col0 + (sub - 8) * 8 + subr);
      else           grow = col0 + sub * 8 + subr;
      const int cs = cc ^ subr;
      gload16(Bt + (size_t)grow * 512 + k0 + cs * 8, lb + sub * 512);
    }
  };

  f32x4 acc1[4][2], acc2[4][2];
  const f32x4 z = {0.f, 0.f, 0.f, 0.f};
  #pragma unroll
  for (int i = 0; i < 4; i++)
    #pragma unroll
    for (int j = 0; j < 2; j++){ acc1[i][j] = z; acc2[i][j] = z; }

  stage(0, 0);
  stage(1, 1);
  waitcnt_vm<VC>();
  __builtin_amdgcn_s_barrier();
  __builtin_amdgcn_sched_barrier(0);

  #pragma unroll
  for (int t = 0; t < 8; ++t){
    const int cur = t & 1;
    const unsigned short* la = lds + cur * BUFSZ;
    const unsigned short* lb = la + ABUF;

    #pragma unroll
    for (int ks = 0; ks < 2; ks++){
      bf16x8 a0[4], a1[4], b0[2], b1v[2];
      #pragma unroll
      for (int i = 0; i < 4; i++){
        const int ra  = wr * 64 + i * 16 + (lane & 15);
        const int ka  = (ks * 4 + (lane >> 4)) ^ (ra & 7);
        a0[i] = *(const bf16x8*)(la + ra * 64 + ka * 8);
        const int ra1 = ra + 1;
        const int ka1 = (ks * 4 + (lane >> 4)) ^ (ra1 & 7);
        a1[i] = *(const bf16x8*)(la + ra1 * 64 + ka1 * 8);
      }
      #pragma unroll
      for (int j = 0; j < 2; j++){
        const int rb = wc * 32 + j * 16 + (lane & 15);
        const int kb = (ks * 4 + (lane >> 4)) ^ (rb & 7);
        b0[j] = *(const bf16x8*)(lb + rb * 64 + kb * 8);
        if (MODE == 0) b1v[j] = *(const bf16x8*)(lb + (64 + rb) * 64 + kb * 8);
      }
      if (ks == 1){
        asm volatile("s_waitcnt lgkmcnt(0)" ::: "memory");
        __builtin_amdgcn_sched_barrier(0);
        __builtin_amdgcn_s_barrier();
        __builtin_amdgcn_sched_barrier(0);
        if (t + 2 < 8) stage(t + 2, cur);
      }
      __builtin_amdgcn_s_setprio(1);
      #pragma unroll
      for (int i = 0; i < 4; i++)
        #pragma unroll
        for (int j = 0; j < 2; j++){
          if (MODE == 0){
            acc1[i][j] = __builtin_amdgcn_mfma_f32_16x16x32_bf16(a0[i], b0[j],  acc1[i][j], 0, 0, 0);
            acc2[i][j] = __builtin_amdgcn_mfma_f32_16x16x32_bf16(a1[i], b1v[j], acc2[i][j], 0, 0, 0);
          } else {
            acc1[i][j] = __builtin_amdgcn_mfma_f32_16x16x32_bf16(a1[i], b0[j], acc1[i][j], 0, 0, 0); // F[s]
            acc2[i][j] = __builtin_amdgcn_mfma_f32_16x16x32_bf16(a0[i], b0[j], acc2[i][j], 0, 0, 0); // F[s-1]
          }
        }
      __builtin_amdgcn_s_setprio(0);
    }

    if (t < 7){
      if (t + 2 < 8) waitcnt_vm<VC>();
      else           waitcnt_vm<0>();
      __builtin_amdgcn_s_barrier();
      __builtin_amdgcn_sched_barrier(0);
    }
  }

  const int r4 = (lane >> 4) * 4;
  const int cl = lane & 15;
  if (MODE == 0){
    #pragma unroll
    for (int j = 0; j < 2; j++){
      const int col = col0 + wc * 32 + j * 16 + cl;
      const float bv = bias[col];
      #pragma unroll
      for (int i = 0; i < 4; i++){
        #pragma unroll
        for (int r = 0; r < 4; r++){
          const int s = rowA0 + wr * 64 + i * 16 + r4 + r;
          const float v = tanhf(acc1[i][j][r] + acc2[i][j][r] + bv);
          act_pad[(size_t)(s + 1) * 512 + col] = ((s & 2047) == 2047) ? 0 : f2bf(v);
        }
      }
    }
  } else {
    const float dt = 1.f / (1.f + expf(-cfl[0]));
    #pragma unroll
    for (int j = 0; j < 2; j++){
      const int col = col0 + wc * 32 + j * 16 + cl;
      const float bv = bias[col];
      #pragma unroll
      for (int i = 0; i < 4; i++){
        #pragma unroll
        for (int r = 0; r < 4; r++){
          const int s = rowA0 + wr * 64 + i * 16 + r4 + r;
          const float fc = ((s & 2047) == 2047) ? 0.f : softplus_f(acc1[i][j][r] + bv);
          const float fp = ((s & 2047) == 0)    ? 0.f : softplus_f(acc2[i][j][r] + bv);
          const size_t o = (size_t)s * 512 + col;
          const float mv = fmaxf(b2f(m16[o]) + dt * (fp - fc), 1e-6f);
          m16[o] = f2bf(mv);
        }
      }
    }
  }
}

// ---------------------------------------------------------------------------
extern "C" void kernel_launch(void* const* d_in, const int* in_sizes, int n_in,
                              void* d_out, int out_size, void* d_ws, size_t ws_size,
                              hipStream_t stream) {
  const int*   x      = (const int*)  d_in[0];
  const float* emb    = (const float*)d_in[1];
  const float* w_mass = (const float*)d_in[2];
  const float* b_mass = (const float*)d_in[3];
  const float* w_f1   = (const float*)d_in[4];
  const float* b_f1   = (const float*)d_in[5];
  const float* w_f2   = (const float*)d_in[6];
  const float* b_f2   = (const float*)d_in[7];
  const float* cfl    = (const float*)d_in[8];
  const float* w_dec  = (const float*)d_in[9];
  const float* b_dec  = (const float*)d_in[10];
  float* out = (float*)d_out;

  char* ws = (char*)d_ws;
  size_t off = 0;
  auto alloc = [&](size_t bytes) -> void* {
    void* p = ws + off;
    off += (bytes + 255) & ~(size_t)255;
    return p;
  };
  unsigned short* wTdec   = (unsigned short*)alloc((size_t)32000 * 512 * 2);
  unsigned short* eA      = (unsigned short*)alloc((size_t)4096 * 512 * 2);
  unsigned short* wTmass  = (unsigned short*)alloc((size_t)512 * 512 * 2);
  unsigned short* wTf1    = (unsigned short*)alloc((size_t)1024 * 512 * 2);
  unsigned short* wTf2    = (unsigned short*)alloc((size_t)512 * 512 * 2);
  unsigned short* m16     = (unsigned short*)alloc((size_t)4104 * 512 * 2);  // rows 4096..4103: zero pad / stage slack
  unsigned short* act_pad = (unsigned short*)alloc((size_t)4104 * 512 * 2);  // row 0 zero pad

  hipFuncSetAttribute(reinterpret_cast<const void*>(&gemmDec),
                      hipFuncAttributeMaxDynamicSharedMemorySize, 49152);
  hipFuncSetAttribute(reinterpret_cast<const void*>(&fluxK<0>),
                      hipFuncAttributeMaxDynamicSharedMemorySize, 67584);
  hipFuncSetAttribute(reinterpret_cast<const void*>(&fluxK<1>),
                      hipFuncAttributeMaxDynamicSharedMemorySize, 51200);

  const dim3 b256(256);
  k_prep<<<19073, b256, 0, stream>>>(w_mass, w_f1, w_f2, w_dec, x, emb,
                                     wTmass, wTf1, wTf2, wTdec, eA,
                                     m16 + (size_t)4096 * 512, act_pad);

  // m = softplus(e @ w_mass + b_mass) + eps  (bf16 carry)
  gemmP<128, 64, 2, 2, 8, 1><<<256, b256, 49152, stream>>>(eA, wTmass, b_mass, m16, 512, 32);

  constexpr int FLUXA_LDS = (17 * 512 + 16 * 512) * 2 * 2;  // 67584 B
  constexpr int FLUXB_LDS = (17 * 512 +  8 * 512) * 2 * 2;  // 51200 B
  for (int it = 0; it < 3; ++it){
    fluxK<0><<<dim3(32, 8), b256, FLUXA_LDS, stream>>>(m16, wTf1, b_f1, nullptr,
                                                       nullptr, act_pad);
    fluxK<1><<<dim3(32, 8), b256, FLUXB_LDS, stream>>>(act_pad, wTf2, b_f2, cfl,
                                                       m16, nullptr);
  }

  // logits = m @ w_dec + b_dec -> f32 [4096, 32000]
  // (4000 WGs = 16 x 250, BK=32 dbuf 48 KiB, 2 blocks/CU)
  gemmDec<<<4000, dim3(512), 49152, stream>>>(m16, wTdec, b_dec, out, 32000, 16);
}

// Round 17
// 298.183 us; speedup vs baseline: 1.7794x; 1.7794x over previous
//
#include <hip/hip_runtime.h>
#include <hip/hip_bf16.h>

#define DEV static __device__ __forceinline__

typedef __attribute__((ext_vector_type(4))) float f32x4;
typedef __attribute__((ext_vector_type(8))) short bf16x8;

DEV unsigned short f2bf(float x){
  __hip_bfloat16 h = __float2bfloat16(x);
  return __builtin_bit_cast(unsigned short, h);
}
DEV float b2f(unsigned short u){
  __hip_bfloat16 h = __builtin_bit_cast(__hip_bfloat16, u);
  return __bfloat162float(h);
}
DEV float softplus_f(float x){ return fmaxf(x, 0.f) + log1pf(expf(-fabsf(x))); }

DEV void gload16(const void* g, void* l){
  __builtin_amdgcn_global_load_lds((const __attribute__((address_space(1))) void*)g,
                                   (__attribute__((address_space(3))) void*)l, 16, 0, 0);
}

template<int N> DEV void waitcnt_vm(){
  if constexpr (N == 0) asm volatile("s_waitcnt vmcnt(0)" ::: "memory");
  else if constexpr (N == 3) asm volatile("s_waitcnt vmcnt(3)" ::: "memory");
  else if constexpr (N == 5) asm volatile("s_waitcnt vmcnt(5)" ::: "memory");
  else if constexpr (N == 6) asm volatile("s_waitcnt vmcnt(6)" ::: "memory");
  else if constexpr (N == 7) asm volatile("s_waitcnt vmcnt(7)" ::: "memory");
  else if constexpr (N == 8) asm volatile("s_waitcnt vmcnt(8)" ::: "memory");
}

// ---------------------------------------------------------------------------
// Merged prep: [0,1024) four 512x512 transposes; [1024,17024) w_dec transpose;
// [17024,19072) gather (2 rows/block); 19072 pad-row zeroing.  256 thr.
__global__ void k_prep(const float* __restrict__ w_mass, const float* __restrict__ w_f1,
                       const float* __restrict__ w_f2, const float* __restrict__ w_dec,
                       const int* __restrict__ x, const float* __restrict__ emb,
                       unsigned short* __restrict__ wTmass, unsigned short* __restrict__ wTf1,
                       unsigned short* __restrict__ wTf2, unsigned short* __restrict__ wTdec,
                       unsigned short* __restrict__ eA,
                       unsigned short* __restrict__ m16_pad, unsigned short* __restrict__ act_pad0){
  __shared__ float t[32][33];
  const int b = blockIdx.x;
  const int tid = threadIdx.x;
  if (b >= 17024){
    const int local = b - 17024;
    if (local == 2048){
      if (tid < 128){
        const ushort4 z = {0, 0, 0, 0};
        ((ushort4*)m16_pad)[tid] = z;
        ((ushort4*)act_pad0)[tid] = z;
      }
      return;
    }
    const int row = local * 2 + (tid >> 7);
    const int c   = tid & 127;
    const int idx = x[row];
    const float4 v = ((const float4*)(emb + (size_t)idx * 512))[c];
    ushort4 o; o.x = f2bf(v.x); o.y = f2bf(v.y); o.z = f2bf(v.z); o.w = f2bf(v.w);
    ((ushort4*)(eA + (size_t)row * 512))[c] = o;
    return;
  }
  const float* in; unsigned short* out; int K, N, bx, by;
  if (b < 1024){
    const int z = b >> 8, idx = b & 255;
    bx = idx & 15; by = idx >> 4; K = 512; N = 512;
    switch (z){
      case 0:  in = w_mass;            out = wTmass;            break;
      case 1:  in = w_f1;              out = wTf1;              break;
      case 2:  in = w_f1 + 512 * 512;  out = wTf1 + 512 * 512;  break;
      default: in = w_f2;              out = wTf2;              break;
    }
  } else {
    const int local = b - 1024;
    bx = local % 1000; by = local / 1000; K = 512; N = 32000;
    in = w_dec; out = wTdec;
  }
  const int nt = bx * 32, kt = by * 32;
  const int r  = tid >> 3;
  const int c4 = (tid & 7) * 4;
  const float4 v = *(const float4*)(in + (size_t)(kt + r) * N + nt + c4);
  t[r][c4+0] = v.x; t[r][c4+1] = v.y; t[r][c4+2] = v.z; t[r][c4+3] = v.w;
  __syncthreads();
  ushort4 o;
  o.x = f2bf(t[c4+0][r]); o.y = f2bf(t[c4+1][r]);
  o.z = f2bf(t[c4+2][r]); o.w = f2bf(t[c4+3][r]);
  *(ushort4*)(out + (size_t)(nt + r) * K + kt + c4) = o;
}

// ---------------------------------------------------------------------------
// Pipelined GEMM (mass): C = A @ Bt^T; EPI 1: softplus(x+bias)+eps -> bf16 outBf.
template<int BM, int BN, int WM, int WN, int NT, int EPI>
__global__ __launch_bounds__(WM * WN * 64, 2)
void gemmP(const unsigned short* __restrict__ A, const unsigned short* __restrict__ Bt,
           const float* __restrict__ bias, unsigned short* __restrict__ outBf,
           int N, int nbx)
{
  constexpr int NW = WM * WN;
  constexpr int FA = BM / (WM * 16);
  constexpr int FB = BN / (WN * 16);
  constexpr int GA = BM / (8 * NW);
  constexpr int GB = BN / (8 * NW);
  constexpr int VC = GA + GB;
  constexpr int LA = BM * 64;
  constexpr int LB = BN * 64;
  constexpr int K  = NT * 64;

  extern __shared__ unsigned short lds[];
  const int tid  = threadIdx.x;
  const int lane = tid & 63;
  const int w    = tid >> 6;
  const int wr   = w / WN;
  const int wc   = w % WN;

  const int nwg = gridDim.x;
  const int cpx = nwg >> 3;
  const int swz = ((int)blockIdx.x & 7) * cpx + ((int)blockIdx.x >> 3);
  const int rowA0 = (swz % nbx) * BM;
  const int rowB0 = (swz / nbx) * BN;

  const int subr = lane >> 3;
  const int cc   = lane & 7;

  auto stage = [&](int kt, int buf){
    unsigned short* la = lds + buf * (LA + LB);
    unsigned short* lb = la + LA;
    const int k0 = kt * 64;
    #pragma unroll
    for (int i = 0; i < GA; i++){
      const int sub = w * GA + i;
      const int r   = sub * 8 + subr;
      const int cs  = cc ^ (r & 7);
      gload16(A + (size_t)(rowA0 + r) * K + k0 + cs * 8, la + sub * 512);
    }
    #pragma unroll
    for (int i = 0; i < GB; i++){
      const int sub = w * GB + i;
      const int r   = sub * 8 + subr;
      const int cs  = cc ^ (r & 7);
      gload16(Bt + (size_t)(rowB0 + r) * K + k0 + cs * 8, lb + sub * 512);
    }
  };

  f32x4 acc[FA][FB];
  const f32x4 z = {0.f, 0.f, 0.f, 0.f};
  #pragma unroll
  for (int i = 0; i < FA; i++)
    #pragma unroll
    for (int j = 0; j < FB; j++) acc[i][j] = z;

  stage(0, 0);
  stage(1, 1);
  waitcnt_vm<VC>();
  __builtin_amdgcn_s_barrier();
  __builtin_amdgcn_sched_barrier(0);

  #pragma unroll
  for (int t = 0; t < NT; ++t){
    const int cur = t & 1;
    const unsigned short* la = lds + cur * (LA + LB);
    const unsigned short* lb = la + LA;

    #pragma unroll
    for (int ks = 0; ks < 2; ks++){
      bf16x8 af[FA], bfr[FB];
      #pragma unroll
      for (int i = 0; i < FA; i++){
        const int ra = wr * (BM / WM) + i * 16 + (lane & 15);
        const int ka = (ks * 4 + (lane >> 4)) ^ (ra & 7);
        af[i] = *(const bf16x8*)(la + ra * 64 + ka * 8);
      }
      #pragma unroll
      for (int j = 0; j < FB; j++){
        const int rb = wc * (BN / WN) + j * 16 + (lane & 15);
        const int kb = (ks * 4 + (lane >> 4)) ^ (rb & 7);
        bfr[j] = *(const bf16x8*)(lb + rb * 64 + kb * 8);
      }
      if (ks == 1){
        asm volatile("s_waitcnt lgkmcnt(0)" ::: "memory");
        __builtin_amdgcn_sched_barrier(0);
        __builtin_amdgcn_s_barrier();
        __builtin_amdgcn_sched_barrier(0);
        if (t + 2 < NT) stage(t + 2, cur);
      }
      __builtin_amdgcn_s_setprio(1);
      #pragma unroll
      for (int i = 0; i < FA; i++)
        #pragma unroll
        for (int j = 0; j < FB; j++)
          acc[i][j] = __builtin_amdgcn_mfma_f32_16x16x32_bf16(af[i], bfr[j], acc[i][j], 0, 0, 0);
      __builtin_amdgcn_s_setprio(0);
    }

    if (t < NT - 1){
      if (t + 2 < NT) waitcnt_vm<VC>();
      else            waitcnt_vm<0>();
      __builtin_amdgcn_s_barrier();
      __builtin_amdgcn_sched_barrier(0);
    }
  }

  const int r4 = (lane >> 4) * 4;
  const int cl = lane & 15;
  #pragma unroll
  for (int j = 0; j < FB; j++){
    const int col = rowB0 + wc * (BN / WN) + j * 16 + cl;
    const float bv = bias[col];
    #pragma unroll
    for (int i = 0; i < FA; i++){
      const int row0 = rowA0 + wr * (BM / WM) + i * 16 + r4;
      #pragma unroll
      for (int r = 0; r < 4; r++){
        float v = softplus_f(acc[i][j][r] + bv) + 1e-6f;
        outBf[(size_t)(row0 + r) * N + col] = f2bf(v);
      }
    }
  }
}

// ---------------------------------------------------------------------------
// Decoder GEMM (R14 + nt-stores): 256x128 tile, BK=32, NT=16, 8 waves,
// dbuf 48 KiB, __launch_bounds__(512,4) -> 2 blocks/CU, vectorized epilogue
// with NON-TEMPORAL stores via native ext-vector type (logits never re-read;
// keep A/B panels in L2).
__global__ __launch_bounds__(512, 4)
void gemmDec(const unsigned short* __restrict__ A, const unsigned short* __restrict__ Bt,
             const float* __restrict__ bias, float* __restrict__ out, int N, int nbx)
{
  constexpr int BM = 256, BN = 128, BK = 32, NT = 16;
  constexpr int LA = BM * BK;
  constexpr int LB = BN * BK;
  constexpr int BUF = LA + LB;
  constexpr int K = NT * BK;

  extern __shared__ unsigned short lds[];
  const int tid  = threadIdx.x;
  const int lane = tid & 63;
  const int w    = tid >> 6;
  const int wr   = w >> 1;
  const int wc   = w & 1;

  const int nwg = gridDim.x;
  const int cpx = nwg >> 3;
  const int swz = ((int)blockIdx.x & 7) * cpx + ((int)blockIdx.x >> 3);
  const int rowA0 = (swz % nbx) * BM;
  const int rowB0 = (swz / nbx) * BN;

  const int srow = lane >> 2;
  const int cch  = lane & 3;

  auto stage = [&](int kt, int buf){
    unsigned short* la = lds + buf * BUF;
    unsigned short* lb = la + LA;
    const int k0 = kt * BK;
    #pragma unroll
    for (int i = 0; i < 2; i++){
      const int sub = w * 2 + i;
      const int r   = sub * 16 + srow;
      const int cs  = cch ^ ((r >> 1) & 3);
      gload16(A + (size_t)(rowA0 + r) * K + k0 + cs * 8, la + sub * 512);
    }
    {
      const int sub = w;
      const int r   = sub * 16 + srow;
      const int cs  = cch ^ ((r >> 1) & 3);
      gload16(Bt + (size_t)(rowB0 + r) * K + k0 + cs * 8, lb + sub * 512);
    }
  };

  f32x4 acc[4][4];
  const f32x4 z = {0.f, 0.f, 0.f, 0.f};
  #pragma unroll
  for (int i = 0; i < 4; i++)
    #pragma unroll
    for (int j = 0; j < 4; j++) acc[i][j] = z;

  stage(0, 0);
  stage(1, 1);
  waitcnt_vm<3>();
  __builtin_amdgcn_s_barrier();
  __builtin_amdgcn_sched_barrier(0);

  const int kq = lane >> 4;

  #pragma unroll
  for (int t = 0; t < NT; ++t){
    const int cur = t & 1;
    const unsigned short* la = lds + cur * BUF;
    const unsigned short* lb = la + LA;

    bf16x8 a[4], b[4];
    #pragma unroll
    for (int i = 0; i < 4; i++){
      const int ra = wr * 64 + i * 16 + (lane & 15);
      const int kc = kq ^ ((ra >> 1) & 3);
      a[i] = *(const bf16x8*)(la + ra * 32 + kc * 8);
    }
    #pragma unroll
    for (int j = 0; j < 4; j++){
      const int rb = wc * 64 + j * 16 + (lane & 15);
      const int kc = kq ^ ((rb >> 1) & 3);
      b[j] = *(const bf16x8*)(lb + rb * 32 + kc * 8);
    }

    asm volatile("s_waitcnt lgkmcnt(0)" ::: "memory");
    __builtin_amdgcn_sched_barrier(0);
    __builtin_amdgcn_s_barrier();
    __builtin_amdgcn_sched_barrier(0);
    if (t + 2 < NT) stage(t + 2, cur);

    __builtin_amdgcn_s_setprio(1);
    #pragma unroll
    for (int i = 0; i < 4; i++)
      #pragma unroll
      for (int j = 0; j < 4; j++)
        acc[i][j] = __builtin_amdgcn_mfma_f32_16x16x32_bf16(a[i], b[j], acc[i][j], 0, 0, 0);
    __builtin_amdgcn_s_setprio(0);

    if (t < NT - 1){
      if (t + 2 < NT) waitcnt_vm<3>();
      else            waitcnt_vm<0>();
      __builtin_amdgcn_s_barrier();
      __builtin_amdgcn_sched_barrier(0);
    }
  }

  float* lds_f = (float*)lds;
  const int r4 = (lane >> 4) * 4;
  const int cl = lane & 15;
  #pragma unroll
  for (int c = 0; c < 4; c++){
    __syncthreads();
    if (wr == c){
      #pragma unroll
      for (int j = 0; j < 4; j++){
        const int col = wc * 64 + j * 16 + cl;
        #pragma unroll
        for (int i = 0; i < 4; i++){
          const int rowl = i * 16 + r4;
          #pragma unroll
          for (int r = 0; r < 4; r++)
            lds_f[(rowl + r) * 132 + col] = acc[i][j][r];
        }
      }
    }
    __syncthreads();
    #pragma unroll
    for (int k = 0; k < 4; k++){
      const int q   = tid + 512 * k;
      const int row = q >> 5;
      const int c0  = (q & 31) * 4;
      f32x4 v = *(f32x4*)&lds_f[row * 132 + c0];
      const f32x4 bv = *(const f32x4*)&bias[rowB0 + c0];
      v += bv;
      __builtin_nontemporal_store(v, (f32x4*)&out[(size_t)(rowA0 + c * 64 + row) * N + rowB0 + c0]);
    }
  }
}

// ---------------------------------------------------------------------------
// Fused flux kernels (R14 64x64 version), dual accumulators via shifted-A.
template<int MODE>
__global__ __launch_bounds__(256, 2)
void fluxK(const unsigned short* __restrict__ A, const unsigned short* __restrict__ Bt,
           const float* __restrict__ bias, const float* __restrict__ cfl,
           unsigned short* __restrict__ m16, unsigned short* __restrict__ act_pad)
{
  constexpr int ASUB = 9;
  constexpr int BSUB = (MODE == 0) ? 16 : 8;
  constexpr int GA = 3;
  constexpr int GB = (MODE == 0) ? 4 : 2;
  constexpr int VC = GA + GB;
  constexpr int ABUF = ASUB * 512;
  constexpr int BBUF = BSUB * 512;
  constexpr int BUFSZ = ABUF + BBUF;

  extern __shared__ unsigned short lds[];
  const int tid  = threadIdx.x;
  const int lane = tid & 63;
  const int w    = tid >> 6;
  const int wr   = w >> 1, wc = w & 1;
  const int rowA0 = blockIdx.x * 64;
  const int col0  = blockIdx.y * 64;
  const int subr = lane >> 3;
  const int cc   = lane & 7;

  auto stage = [&](int kt, int buf){
    unsigned short* la = lds + buf * BUFSZ;
    unsigned short* lb = la + ABUF;
    const int k0 = kt * 64;
    #pragma unroll
    for (int i = 0; i < GA; i++){
      const int si  = w * GA + i;
      const int sub = si > 8 ? 8 : si;
      const int r   = sub * 8 + subr;
      const int cs  = cc ^ subr;
      gload16(A + (size_t)(rowA0 + r) * 512 + k0 + cs * 8, la + sub * 512);
    }
    #pragma unroll
    for (int i = 0; i < GB; i++){
      const int sub = w * GB + i;
      int grow;
      if (MODE == 0) grow = (sub < 8) ? (col0 + sub * 8 + subr)
                                      : (512 + col0 + (sub - 8) * 8 + subr);
      else           grow = col0 + sub * 8 + subr;
      const int cs = cc ^ subr;
      gload16(Bt + (size_t)grow * 512 + k0 + cs * 8, lb + sub * 512);
    }
  };

  f32x4 acc1[2][2], acc2[2][2];
  const f32x4 z = {0.f, 0.f, 0.f, 0.f};
  #pragma unroll
  for (int i = 0; i < 2; i++)
    #pragma unroll
    for (int j = 0; j < 2; j++){ acc1[i][j] = z; acc2[i][j] = z; }

  stage(0, 0);
  stage(1, 1);
  waitcnt_vm<VC>();
  __builtin_amdgcn_s_barrier();
  __builtin_amdgcn_sched_barrier(0);

  #pragma unroll
  for (int t = 0; t < 8; ++t){
    const int cur = t & 1;
    const unsigned short* la = lds + cur * BUFSZ;
    const unsigned short* lb = la + ABUF;

    #pragma unroll
    for (int ks = 0; ks < 2; ks++){
      bf16x8 a0[2], a1[2], b0[2], b1v[2];
      #pragma unroll
      for (int i = 0; i < 2; i++){
        const int ra  = wr * 32 + i * 16 + (lane & 15);
        const int ka  = (ks * 4 + (lane >> 4)) ^ (ra & 7);
        a0[i] = *(const bf16x8*)(la + ra * 64 + ka * 8);
        const int ra1 = ra + 1;
        const int ka1 = (ks * 4 + (lane >> 4)) ^ (ra1 & 7);
        a1[i] = *(const bf16x8*)(la + ra1 * 64 + ka1 * 8);
      }
      #pragma unroll
      for (int j = 0; j < 2; j++){
        const int rb = wc * 32 + j * 16 + (lane & 15);
        const int kb = (ks * 4 + (lane >> 4)) ^ (rb & 7);
        b0[j] = *(const bf16x8*)(lb + rb * 64 + kb * 8);
        if (MODE == 0) b1v[j] = *(const bf16x8*)(lb + (64 + rb) * 64 + kb * 8);
      }
      if (ks == 1){
        asm volatile("s_waitcnt lgkmcnt(0)" ::: "memory");
        __builtin_amdgcn_sched_barrier(0);
        __builtin_amdgcn_s_barrier();
        __builtin_amdgcn_sched_barrier(0);
        if (t + 2 < 8) stage(t + 2, cur);
      }
      __builtin_amdgcn_s_setprio(1);
      #pragma unroll
      for (int i = 0; i < 2; i++)
        #pragma unroll
        for (int j = 0; j < 2; j++){
          if (MODE == 0){
            acc1[i][j] = __builtin_amdgcn_mfma_f32_16x16x32_bf16(a0[i], b0[j],  acc1[i][j], 0, 0, 0);
            acc2[i][j] = __builtin_amdgcn_mfma_f32_16x16x32_bf16(a1[i], b1v[j], acc2[i][j], 0, 0, 0);
          } else {
            acc1[i][j] = __builtin_amdgcn_mfma_f32_16x16x32_bf16(a1[i], b0[j], acc1[i][j], 0, 0, 0); // F[s]
            acc2[i][j] = __builtin_amdgcn_mfma_f32_16x16x32_bf16(a0[i], b0[j], acc2[i][j], 0, 0, 0); // F[s-1]
          }
        }
      __builtin_amdgcn_s_setprio(0);
    }

    if (t < 7){
      if (t + 2 < 8) waitcnt_vm<VC>();
      else           waitcnt_vm<0>();
      __builtin_amdgcn_s_barrier();
      __builtin_amdgcn_sched_barrier(0);
    }
  }

  const int r4 = (lane >> 4) * 4;
  const int cl = lane & 15;
  if (MODE == 0){
    #pragma unroll
    for (int j = 0; j < 2; j++){
      const int col = col0 + wc * 32 + j * 16 + cl;
      const float bv = bias[col];
      #pragma unroll
      for (int i = 0; i < 2; i++){
        #pragma unroll
        for (int r = 0; r < 4; r++){
          const int s = rowA0 + wr * 32 + i * 16 + r4 + r;
          const float v = tanhf(acc1[i][j][r] + acc2[i][j][r] + bv);
          act_pad[(size_t)(s + 1) * 512 + col] = ((s & 2047) == 2047) ? 0 : f2bf(v);
        }
      }
    }
  } else {
    const float dt = 1.f / (1.f + expf(-cfl[0]));
    #pragma unroll
    for (int j = 0; j < 2; j++){
      const int col = col0 + wc * 32 + j * 16 + cl;
      const float bv = bias[col];
      #pragma unroll
      for (int i = 0; i < 2; i++){
        #pragma unroll
        for (int r = 0; r < 4; r++){
          const int s = rowA0 + wr * 32 + i * 16 + r4 + r;
          const float fc = ((s & 2047) == 2047) ? 0.f : softplus_f(acc1[i][j][r] + bv);
          const float fp = ((s & 2047) == 0)    ? 0.f : softplus_f(acc2[i][j][r] + bv);
          const size_t o = (size_t)s * 512 + col;
          const float mv = fmaxf(b2f(m16[o]) + dt * (fp - fc), 1e-6f);
          m16[o] = f2bf(mv);
        }
      }
    }
  }
}

// ---------------------------------------------------------------------------
extern "C" void kernel_launch(void* const* d_in, const int* in_sizes, int n_in,
                              void* d_out, int out_size, void* d_ws, size_t ws_size,
                              hipStream_t stream) {
  const int*   x      = (const int*)  d_in[0];
  const float* emb    = (const float*)d_in[1];
  const float* w_mass = (const float*)d_in[2];
  const float* b_mass = (const float*)d_in[3];
  const float* w_f1   = (const float*)d_in[4];
  const float* b_f1   = (const float*)d_in[5];
  const float* w_f2   = (const float*)d_in[6];
  const float* b_f2   = (const float*)d_in[7];
  const float* cfl    = (const float*)d_in[8];
  const float* w_dec  = (const float*)d_in[9];
  const float* b_dec  = (const float*)d_in[10];
  float* out = (float*)d_out;

  char* ws = (char*)d_ws;
  size_t off = 0;
  auto alloc = [&](size_t bytes) -> void* {
    void* p = ws + off;
    off += (bytes + 255) & ~(size_t)255;
    return p;
  };
  unsigned short* wTdec   = (unsigned short*)alloc((size_t)32000 * 512 * 2);
  unsigned short* eA      = (unsigned short*)alloc((size_t)4096 * 512 * 2);
  unsigned short* wTmass  = (unsigned short*)alloc((size_t)512 * 512 * 2);
  unsigned short* wTf1    = (unsigned short*)alloc((size_t)1024 * 512 * 2);
  unsigned short* wTf2    = (unsigned short*)alloc((size_t)512 * 512 * 2);
  unsigned short* m16     = (unsigned short*)alloc((size_t)4097 * 512 * 2);  // +1 zero pad row
  unsigned short* act_pad = (unsigned short*)alloc((size_t)4104 * 512 * 2);  // row 0 zero pad

  (void)hipFuncSetAttribute(reinterpret_cast<const void*>(&gemmDec),
                            hipFuncAttributeMaxDynamicSharedMemorySize, 49152);
  (void)hipFuncSetAttribute(reinterpret_cast<const void*>(&fluxK<0>),
                            hipFuncAttributeMaxDynamicSharedMemorySize, 65536);
  (void)hipFuncSetAttribute(reinterpret_cast<const void*>(&fluxK<1>),
                            hipFuncAttributeMaxDynamicSharedMemorySize, 65536);

  const dim3 b256(256);
  k_prep<<<19073, b256, 0, stream>>>(w_mass, w_f1, w_f2, w_dec, x, emb,
                                     wTmass, wTf1, wTf2, wTdec, eA,
                                     m16 + (size_t)4096 * 512, act_pad);

  // m = softplus(e @ w_mass + b_mass) + eps  (bf16 carry)
  gemmP<128, 64, 2, 2, 8, 1><<<256, b256, 49152, stream>>>(eA, wTmass, b_mass, m16, 512, 32);

  constexpr int FLUXA_LDS = (9 * 512 + 16 * 512) * 2 * 2;  // 51200 B
  constexpr int FLUXB_LDS = (9 * 512 +  8 * 512) * 2 * 2;  // 34816 B
  for (int it = 0; it < 3; ++it){
    fluxK<0><<<dim3(64, 8), b256, FLUXA_LDS, stream>>>(m16, wTf1, b_f1, nullptr,
                                                       nullptr, act_pad);
    fluxK<1><<<dim3(64, 8), b256, FLUXB_LDS, stream>>>(act_pad, wTf2, b_f2, cfl,
                                                       m16, nullptr);
  }

  // logits = m @ w_dec + b_dec -> f32 [4096, 32000]
  // (4000 WGs = 16 x 250, BK=32 dbuf 48 KiB, 2 blocks/CU, nt stores)
  gemmDec<<<4000, dim3(512), 49152, stream>>>(m16, wTdec, b_dec, out, 32000, 16);
}